// Round 1
// 160.428 us; speedup vs baseline: 1.0653x; 1.0653x over previous
//
#include <hip/hip_runtime.h>

#define NODE_DIM 128
#define OUT_DIM  64
#define NEG_SLOPE 0.01f

typedef __attribute__((ext_vector_type(8))) short short8;
typedef __attribute__((ext_vector_type(4))) short short4v;
typedef __attribute__((ext_vector_type(4))) float float4e;

__device__ __forceinline__ unsigned short f2bf(float f) {
    unsigned u = __float_as_uint(f);
    unsigned r = (u + 0x7FFFu + ((u >> 16) & 1u)) >> 16;
    return (unsigned short)r;
}
__device__ __forceinline__ float bf2f(unsigned short v) {
    return __uint_as_float((unsigned)v << 16);
}
__device__ __forceinline__ void split_bf(float v, short& hi, short& lo) {
    unsigned short h = f2bf(v);
    float r = v - bf2f(h);
    hi = (short)h;
    lo = (short)f2bf(r);
}

// ---- K0: precompute W fragments (bf16 hi/lo) in MFMA B-operand order -------
// Slot f = (c*4 + t)*64 + lane holds 8 bf16: W[t*32 + (lane>>4)*8 + j][c*16 + (lane&15)]
// Blocks >0 zero the deg array (fused so the separate memset dispatch goes away).
__global__ __launch_bounds__(256) void k_wprep(const float* __restrict__ Wf,
                                               short* __restrict__ bhi,
                                               short* __restrict__ blo,
                                               int* __restrict__ deg, int N) {
    if (blockIdx.x > 0) {
        int i = (blockIdx.x - 1) * 256 + threadIdx.x;
        if (i < N) deg[i] = 0;
        return;
    }
    int s0 = threadIdx.x;
    for (int s = s0; s < 1024; s += 256) {
        int combo = s >> 6;             // 0..15
        int lane  = s & 63;
        int c = combo >> 2, t = combo & 3;
        int n = lane & 15, quad = lane >> 4;
        int col = c * 16 + n;
        #pragma unroll
        for (int j = 0; j < 8; ++j) {
            int k = t * 32 + quad * 8 + j;
            short hi, lo;
            split_bf(Wf[k * OUT_DIM + col], hi, lo);
            bhi[s * 8 + j] = hi;
            blo[s * 8 + j] = lo;
        }
    }
}

// ---- K1 (fused): blocks [0,PB): MFMA projection; blocks [PB,..): count+rank -
// Proj: 64 nodes/block, one 16x64 tile per wave via mfma_f32_16x16x32_bf16.
// Split-precision: z = hi*Whi + hi*Wlo + lo*Whi (fp32 acc), rel err ~1e-5.
__global__ __launch_bounds__(256) void k_proj_count(const float* __restrict__ h,
                                                    const short* __restrict__ bhi,
                                                    const short* __restrict__ blo,
                                                    const float* __restrict__ Wa,
                                                    unsigned short* __restrict__ zbf,
                                                    float* __restrict__ s_src,
                                                    float* __restrict__ s_dst,
                                                    const int* __restrict__ dst,
                                                    int* __restrict__ deg,
                                                    int* __restrict__ rank,
                                                    int N, int E, int PB, int CB) {
    if (blockIdx.x >= (unsigned)PB) {
        int nthreads = CB * 256;
        for (int i = (blockIdx.x - PB) * 256 + threadIdx.x; i < E; i += nthreads)
            rank[i] = atomicAdd(deg + dst[i], 1);
        return;
    }
    const int t    = threadIdx.x;
    const int wv   = t >> 6;
    const int lane = t & 63;
    const int m    = lane & 15;
    const int quad = lane >> 4;
    const int row0 = blockIdx.x * 64 + wv * 16;

    int rowc = row0 + m; if (rowc > N - 1) rowc = N - 1;
    const float* hrow = h + (size_t)rowc * NODE_DIM;
    short8 Ahi[4], Alo[4];
    #pragma unroll
    for (int t4 = 0; t4 < 4; ++t4) {
        float4e v0 = *(const float4e*)(hrow + t4 * 32 + quad * 8);
        float4e v1 = *(const float4e*)(hrow + t4 * 32 + quad * 8 + 4);
        #pragma unroll
        for (int j = 0; j < 4; ++j) {
            short hi, lo;
            split_bf(v0[j], hi, lo);
            Ahi[t4][j] = hi; Alo[t4][j] = lo;
            split_bf(v1[j], hi, lo);
            Ahi[t4][4 + j] = hi; Alo[t4][4 + j] = lo;
        }
    }

    float ps[4] = {0.f, 0.f, 0.f, 0.f};
    float pd[4] = {0.f, 0.f, 0.f, 0.f};

    #pragma unroll
    for (int c = 0; c < 4; ++c) {
        float4e acc = {0.f, 0.f, 0.f, 0.f};
        #pragma unroll
        for (int t4 = 0; t4 < 4; ++t4) {
            int slot = (c * 4 + t4) * 64 + lane;
            short8 bh = *(const short8*)(bhi + slot * 8);
            short8 bl = *(const short8*)(blo + slot * 8);
            acc = __builtin_amdgcn_mfma_f32_16x16x32_bf16(Alo[t4], bh, acc, 0, 0, 0);
            acc = __builtin_amdgcn_mfma_f32_16x16x32_bf16(Ahi[t4], bl, acc, 0, 0, 0);
            acc = __builtin_amdgcn_mfma_f32_16x16x32_bf16(Ahi[t4], bh, acc, 0, 0, 0);
        }
        int col = c * 16 + m;
        float was = Wa[col];
        float wad = Wa[OUT_DIM + col];
        #pragma unroll
        for (int r = 0; r < 4; ++r) {
            int nrow = row0 + quad * 4 + r;
            if (nrow < N) zbf[(size_t)nrow * OUT_DIM + col] = f2bf(acc[r]);
            ps[r] = fmaf(acc[r], was, ps[r]);
            pd[r] = fmaf(acc[r], wad, pd[r]);
        }
    }

    #pragma unroll
    for (int r = 0; r < 4; ++r) {
        #pragma unroll
        for (int off = 1; off < 16; off <<= 1) {
            ps[r] += __shfl_xor(ps[r], off, 64);
            pd[r] += __shfl_xor(pd[r], off, 64);
        }
    }
    if (m == 0) {
        #pragma unroll
        for (int r = 0; r < 4; ++r) {
            int nrow = row0 + quad * 4 + r;
            if (nrow < N) { s_src[nrow] = ps[r]; s_dst[nrow] = pd[r]; }
        }
    }
}

// ---- K2: per-block exclusive scan of deg -> rstart(local); bsum[b] = total
__global__ __launch_bounds__(256) void k_scan_local(const int* __restrict__ deg,
                                                    int* __restrict__ rstart,
                                                    int* __restrict__ bsum, int N) {
    __shared__ int s[256];
    int i = blockIdx.x * 256 + threadIdx.x;
    int t = threadIdx.x;
    int v = (i < N) ? deg[i] : 0;
    s[t] = v;
    __syncthreads();
    #pragma unroll
    for (int off = 1; off < 256; off <<= 1) {
        int u = (t >= off) ? s[t - off] : 0;
        __syncthreads();
        s[t] += u;
        __syncthreads();
    }
    if (i < N) rstart[i] = s[t] - v;
    if (t == 255) bsum[blockIdx.x] = s[255];
}

// ---- K3: every block redundantly scans the spine, adds its offset
__global__ __launch_bounds__(256) void k_scan_add(int* __restrict__ rstart,
                                                  const int* __restrict__ bsum,
                                                  int N, int nb) {
    __shared__ int s[256];
    int t = threadIdx.x;
    s[t] = (t < nb) ? bsum[t] : 0;
    __syncthreads();
    #pragma unroll
    for (int off = 1; off < 256; off <<= 1) {
        int u = (t >= off) ? s[t - off] : 0;
        __syncthreads();
        s[t] += u;
        __syncthreads();
    }
    int boff = (blockIdx.x > 0) ? s[blockIdx.x - 1] : 0;
    int i = blockIdx.x * 256 + t;
    if (i < N) rstart[i] += boff;
}

// ---- K4: place src index at rstart[dst] + rank  (4 B records, no atomics)
__global__ __launch_bounds__(256) void k_place(const int* __restrict__ src,
                                               const int* __restrict__ dst,
                                               const int* __restrict__ rank,
                                               const int* __restrict__ rstart,
                                               int* __restrict__ spk, int E) {
    int i = blockIdx.x * 256 + threadIdx.x;
    if (i >= E) return;
    spk[rstart[dst[i]] + rank[i]] = src[i];
}

// ---- K5: one wave per dst node. Lane owns 4 output columns ((lane&15)*4..+3);
// each 16-lane quad handles a different edge, so one dwordx2 load fetches FOUR
// complete 128 B z-rows per instruction (512 B, zero waste). Tail edges are
// free: lanes >= m carry xl=0 / sl=0, so their fmas add 0.
__global__ __launch_bounds__(256) void k_agg(const int* __restrict__ rstart,
                                             const int* __restrict__ deg,
                                             const int* __restrict__ spk,
                                             const float* __restrict__ s_src,
                                             const float* __restrict__ s_dst,
                                             const unsigned short* __restrict__ zbf,
                                             float* __restrict__ out, int N) {
    int node = blockIdx.x * 4 + (threadIdx.x >> 6);
    int lane = threadIdx.x & 63;
    if (node >= N) return;
    int quad = lane >> 4;
    int col4 = (lane & 15) * 4;
    int rs = rstart[node];
    int dg = deg[node];
    float sdst = s_dst[node];
    const int* pk = spk + rs;
    float a0 = 0.f, a1 = 0.f, a2 = 0.f, a3 = 0.f;
    float den = 0.f;
    for (int base = 0; base < dg; base += 64) {
        int m = dg - base; if (m > 64) m = 64;
        int sl = 0; float xl = 0.f;
        if (lane < m) {
            sl = pk[base + lane];
            float e = s_src[sl] + sdst;
            e = (e > 0.f) ? e : e * NEG_SLOPE;
            xl = __expf(e);
        }
        den += xl;
        for (int j = 0; j < m; j += 16) {
            #pragma unroll
            for (int g = 0; g < 4; ++g) {
                int eidx = j + g * 4 + quad;            // < 64 always
                int   ss = __shfl(sl, eidx, 64);
                float xx = __shfl(xl, eidx, 64);
                short4v zv = *(const short4v*)(zbf + ((unsigned)ss << 6) + col4);
                a0 = fmaf(xx, bf2f((unsigned short)zv[0]), a0);
                a1 = fmaf(xx, bf2f((unsigned short)zv[1]), a1);
                a2 = fmaf(xx, bf2f((unsigned short)zv[2]), a2);
                a3 = fmaf(xx, bf2f((unsigned short)zv[3]), a3);
            }
        }
    }
    // fold the 4 quad-partials
    a0 += __shfl_xor(a0, 16, 64); a0 += __shfl_xor(a0, 32, 64);
    a1 += __shfl_xor(a1, 16, 64); a1 += __shfl_xor(a1, 32, 64);
    a2 += __shfl_xor(a2, 16, 64); a2 += __shfl_xor(a2, 32, 64);
    a3 += __shfl_xor(a3, 16, 64); a3 += __shfl_xor(a3, 32, 64);
    #pragma unroll
    for (int off = 32; off > 0; off >>= 1) den += __shfl_xor(den, off, 64);
    if (quad == 0) {
        float4e o;
        o[0] = (dg > 0) ? a0 / den : 0.f;
        o[1] = (dg > 0) ? a1 / den : 0.f;
        o[2] = (dg > 0) ? a2 / den : 0.f;
        o[3] = (dg > 0) ? a3 / den : 0.f;
        *(float4e*)(out + (size_t)node * OUT_DIM + col4) = o;
    }
}

extern "C" void kernel_launch(void* const* d_in, const int* in_sizes, int n_in,
                              void* d_out, int out_size, void* d_ws, size_t ws_size,
                              hipStream_t stream) {
    const float* h   = (const float*)d_in[0];
    const int*   src = (const int*)d_in[1];
    const int*   dst = (const int*)d_in[2];
    const float* Wf  = (const float*)d_in[3];
    const float* Wa  = (const float*)d_in[4];
    const int N = in_sizes[0] / NODE_DIM;
    const int E = in_sizes[1];
    float* out = (float*)d_out;

    char* ws = (char*)d_ws;
    size_t off = 0;
    unsigned short* zbf = (unsigned short*)(ws + off); off += (size_t)N * OUT_DIM * sizeof(unsigned short);
    int*   spk    = (int*)(ws + off);   off += (size_t)E * sizeof(int);
    int*   rank   = (int*)(ws + off);   off += (size_t)E * sizeof(int);
    int*   deg    = (int*)(ws + off);   off += (size_t)N * sizeof(int);
    int*   rstart = (int*)(ws + off);   off += (size_t)N * sizeof(int);
    float* s_src  = (float*)(ws + off); off += (size_t)N * sizeof(float);
    float* s_dst  = (float*)(ws + off); off += (size_t)N * sizeof(float);
    short* bhi    = (short*)(ws + off); off += 1024 * 8 * sizeof(short);
    short* blo    = (short*)(ws + off); off += 1024 * 8 * sizeof(short);
    int*   bsum   = (int*)(ws + off);   off += 256 * sizeof(int);

    const int PB = (N + 63) / 64;            // proj blocks (782)
    const int CB = 1024;                     // count blocks
    const int nbN = (N + 255) / 256;         // 196
    const int nbE = (E + 255) / 256;

    k_wprep<<<1 + nbN, 256, 0, stream>>>(Wf, bhi, blo, deg, N);
    k_proj_count<<<PB + CB, 256, 0, stream>>>(h, bhi, blo, Wa, zbf, s_src, s_dst,
                                              dst, deg, rank, N, E, PB, CB);
    k_scan_local<<<nbN, 256, 0, stream>>>(deg, rstart, bsum, N);
    k_scan_add<<<nbN, 256, 0, stream>>>(rstart, bsum, N, nbN);
    k_place<<<nbE, 256, 0, stream>>>(src, dst, rank, rstart, spk, E);
    k_agg<<<(N + 3) / 4, 256, 0, stream>>>(rstart, deg, spk, s_src, s_dst, zbf, out, N);
}